// Round 6
// baseline (687.475 us; speedup 1.0000x reference)
//
#include <hip/hip_runtime.h>

#define B_ 8192
#define T_ 256
#define H_ 128
#define ROWS 32
#define NTH 1024

typedef __attribute__((ext_vector_type(4))) float f32x4;
typedef __attribute__((ext_vector_type(4))) short short4_t;
typedef __attribute__((ext_vector_type(8))) short short8_t;
typedef __attribute__((ext_vector_type(8))) _Float16 half8;
typedef __attribute__((ext_vector_type(2))) _Float16 half2_t;
typedef __attribute__((ext_vector_type(2))) unsigned int uint2_t;
typedef __attribute__((ext_vector_type(4))) unsigned int uint4_t;

__device__ __forceinline__ float fast_exp(float x) {
    return __builtin_amdgcn_exp2f(x * 1.4426950408889634f);
}
__device__ __forceinline__ float sigm(float x) {
    return __builtin_amdgcn_rcpf(1.0f + fast_exp(-x));
}
__device__ __forceinline__ float tanh_f(float x) {
    return 1.0f - 2.0f * __builtin_amdgcn_rcpf(1.0f + fast_exp(2.0f * x));
}
__device__ __forceinline__ short h16bits(float v) {
    return __builtin_bit_cast(short, (_Float16)v);
}
__device__ __forceinline__ float h16f(short s) {
    return (float)__builtin_bit_cast(_Float16, s);
}
__device__ __forceinline__ unsigned pk2(float lo, float hi) {
    return __builtin_bit_cast(unsigned, __builtin_amdgcn_cvt_pkrtz(lo, hi));
}
__device__ __forceinline__ half2_t h2(unsigned u) {
    return __builtin_bit_cast(half2_t, u);
}
__device__ __forceinline__ unsigned pkadd(unsigned a, unsigned b) {
    return __builtin_bit_cast(unsigned, (half2_t)(h2(a) + h2(b)));
}
// segmented (16-lane rows) sum of packed f16 pair; valid in lane 16g+15
__device__ __forceinline__ unsigned red16_pk(unsigned v) {
    v = pkadd(v, (unsigned)__builtin_amdgcn_update_dpp(0, (int)v, 0x111, 0xf, 0xf, true));
    v = pkadd(v, (unsigned)__builtin_amdgcn_update_dpp(0, (int)v, 0x112, 0xf, 0xf, true));
    v = pkadd(v, (unsigned)__builtin_amdgcn_update_dpp(0, (int)v, 0x114, 0xf, 0xf, true));
    v = pkadd(v, (unsigned)__builtin_amdgcn_update_dpp(0, (int)v, 0x118, 0xf, 0xf, true));
    return v;
}

// 1024-thread block (16 waves), 32 batch rows, 1 block/CU, 4 waves/SIMD.
// Gate-split wave specialization:
//   waves 0..7  (RZ): R,Z gates for H-cols [16w,16w+16)   — 64 weight VGPRs
//   waves 8..15 (N) : Ni,Nh for H-cols [16(w-8),...)      — 32 weight VGPRs
// Per step: P0 (all: c_t + feat build) | B1 | MFMAs (RZ:32, N:16) ;
// RZ write packed (r,z) to rz_s | B2 | N: gates, h-update, h-frags, c/p
// partials | B3.  3 barriers, matched in both divergent paths.
// A-frag layout: elem (row i, k) -> chunk[(i + 16*((k&31)>>3))*8 + (k&7)]
__global__ __launch_bounds__(NTH) void brits_kernel(
    const float* __restrict__ x_seq, const float* __restrict__ m_seq,
    const float* __restrict__ Wc_w,  const float* __restrict__ Wc_b,
    const float* __restrict__ Wx_w,  const float* __restrict__ Wx_b,
    const float* __restrict__ W_ih,  const float* __restrict__ W_hh,
    const float* __restrict__ b_ih,  const float* __restrict__ b_hh,
    const float* __restrict__ out_w, const float* __restrict__ out_b,
    float* __restrict__ out)
{
    __shared__ __align__(16) short feat_s[2][4][512];      // 8 KiB
    __shared__ __align__(16) short h_s[2][2][4][512];      // 16 KiB dbuf
    __shared__ __align__(16) short x_all[T_][ROWS];        // 16 KiB
    __shared__ __align__(16) short m_all[T_][ROWS];        // 16 KiB
    __shared__ __align__(16) short comp_sh[ROWS][264];     // 16.5 KiB
    __shared__ __align__(16) short pred_sh[ROWS][264];     // 16.5 KiB
    __shared__ __align__(16) unsigned rz_s[ROWS][132];     // 16.5 KiB (pad 132: 2-way banks)
    __shared__ __align__(16) unsigned part_cp[2][ROWS][12];// 3 KiB dbuf

    const int tid  = threadIdx.x;
    const int lane = tid & 63;
    const int wv   = tid >> 6;          // 0..15
    const int kg   = lane >> 4;
    const int ln16 = lane & 15;
    const int rb   = kg * 4;
    const int row  = tid & 31;          // P0 row
    const int q    = tid >> 5;          // P0 col-quad 0..31 (also init prow)
    const long b0  = (long)blockIdx.x * ROWS;

    const float cb = Wc_b[0];
    const float ob = out_b[0];

    // per-thread feat constants (cols 4q..4q+3)
    const unsigned wxq0 = pk2(Wx_w[4 * q + 0], Wx_w[4 * q + 1]);
    const unsigned wxq1 = pk2(Wx_w[4 * q + 2], Wx_w[4 * q + 3]);
    const unsigned bxq0 = pk2(Wx_b[4 * q + 0], Wx_b[4 * q + 1]);
    const unsigned bxq1 = pk2(Wx_b[4 * q + 2], Wx_b[4 * q + 3]);

    // ---- one-time init ----
    {   // x/m panel: coalesced read, transposed f16 store
        const int pt = row * 8;
        const float* xp = x_seq + (b0 + q) * T_ + pt;
        const float* mp = m_seq + (b0 + q) * T_ + pt;
#pragma unroll
        for (int i = 0; i < 2; ++i) {
            f32x4 xv = *(const f32x4*)(xp + 4 * i);
            f32x4 mv = *(const f32x4*)(mp + 4 * i);
#pragma unroll
            for (int j = 0; j < 4; ++j) {
                x_all[pt + 4 * i + j][q] = h16bits(xv[j]);
                m_all[pt + 4 * i + j][q] = h16bits(mv[j]);
            }
        }
    }
    if (tid < 512) {   // zero h buffer 0 (4096 shorts)
        short8_t z8 = {0, 0, 0, 0, 0, 0, 0, 0};
        *(short8_t*)((short*)h_s + tid * 8) = z8;
    }
    if (tid < ROWS * 12) ((unsigned*)part_cp)[tid] = 0u;   // zero partial buf 0
    __syncthreads();

    // P0: partial-combine -> c_t; comp/pred staging; cooperative feat build
    auto phase0 = [&](int t, int pb) {
        uint4_t u0 = *(const uint4_t*)&part_cp[pb][row][0];
        uint4_t u1 = *(const uint4_t*)&part_cp[pb][row][4];
        unsigned sacc = pkadd(pkadd(pkadd(u0[0], u0[1]), pkadd(u0[2], u0[3])),
                              pkadd(pkadd(u1[0], u1[1]), pkadd(u1[2], u1[3])));
        const half2_t sv = h2(sacc);
        const float c_t = tanh_f((float)sv[0] + cb);
        if (tid < 32) comp_sh[row][t] = h16bits(c_t);
        if (tid >= 32 && tid < 64 && t > 0)
            pred_sh[row][t - 1] = h16bits((float)sv[1] + ob);
        const short ms = m_all[t][row];
        const short xs = x_all[t][row];
        const _Float16 xi = ms ? __builtin_bit_cast(_Float16, xs) : (_Float16)c_t;
        const half2_t xx = {xi, xi};
        half2_t v0 = h2(wxq0) * xx + h2(bxq0);
        half2_t v1 = h2(wxq1) * xx + h2(bxq1);
        const _Float16 zh = (_Float16)0;
        v0[0] = v0[0] > zh ? v0[0] : zh;
        v0[1] = v0[1] > zh ? v0[1] : zh;
        v1[0] = v1[0] > zh ? v1[0] : zh;
        v1[1] = v1[1] > zh ? v1[1] : zh;
        uint2_t st;
        st[0] = __builtin_bit_cast(unsigned, v0);
        st[1] = __builtin_bit_cast(unsigned, v1);
        const int idx = ((row & 15) + 16 * ((q >> 1) & 3)) * 8 + (q & 1) * 4;
        *(uint2_t*)&feat_s[row >> 4][q >> 3][idx] = st;
    };

    if (wv < 8) {
        // ---------------- RZ path ----------------
        const int cH = wv * 16 + ln16;
        const int cR = cH, cZ = cH + 128;
        const float bR  = b_ih[cR] + b_hh[cR];
        const float bZ  = b_ih[cZ] + b_hh[cZ];
        const float bRm = bR + W_ih[cR * 129 + 128];
        const float bZm = bZ + W_ih[cZ * 129 + 128];
        half8 wr[8], wz[8];
#pragma unroll
        for (int kc = 0; kc < 8; ++kc) {
            const float *pr, *pz;
            if (kc < 4) {
                const int off = kc * 32 + kg * 8;
                pr = W_ih + cR * 129 + off;
                pz = W_ih + cZ * 129 + off;
            } else {
                const int off = (kc - 4) * 32 + kg * 8;
                pr = W_hh + cR * 128 + off;
                pz = W_hh + cZ * 128 + off;
            }
#pragma unroll
            for (int e = 0; e < 8; ++e) {
                wr[kc][e] = (_Float16)pr[e];
                wz[kc][e] = (_Float16)pz[e];
            }
        }

        for (int t = 0; t < T_; ++t) {
            const int pb = t & 1;
            phase0(t, pb);
            short4_t m4a = *(const short4_t*)&m_all[t][rb];
            short4_t m4b = *(const short4_t*)&m_all[t][16 + rb];
            f32x4 aR0, aZ0, aR1, aZ1;
#pragma unroll
            for (int e = 0; e < 4; ++e) {
                aR0[e] = m4a[e] ? bRm : bR;
                aZ0[e] = m4a[e] ? bZm : bZ;
                aR1[e] = m4b[e] ? bRm : bR;
                aZ1[e] = m4b[e] ? bZm : bZ;
            }
            __syncthreads();   // B1: feat visible
#pragma unroll
            for (int kc = 0; kc < 4; ++kc) {
                half8 a0 = __builtin_bit_cast(half8, *(const short8_t*)&feat_s[0][kc][lane * 8]);
                half8 a1 = __builtin_bit_cast(half8, *(const short8_t*)&feat_s[1][kc][lane * 8]);
                aR0 = __builtin_amdgcn_mfma_f32_16x16x32_f16(a0, wr[kc], aR0, 0, 0, 0);
                aZ0 = __builtin_amdgcn_mfma_f32_16x16x32_f16(a0, wz[kc], aZ0, 0, 0, 0);
                aR1 = __builtin_amdgcn_mfma_f32_16x16x32_f16(a1, wr[kc], aR1, 0, 0, 0);
                aZ1 = __builtin_amdgcn_mfma_f32_16x16x32_f16(a1, wz[kc], aZ1, 0, 0, 0);
            }
#pragma unroll
            for (int kc = 0; kc < 4; ++kc) {
                half8 a0 = __builtin_bit_cast(half8, *(const short8_t*)&h_s[pb][0][kc][lane * 8]);
                half8 a1 = __builtin_bit_cast(half8, *(const short8_t*)&h_s[pb][1][kc][lane * 8]);
                aR0 = __builtin_amdgcn_mfma_f32_16x16x32_f16(a0, wr[4 + kc], aR0, 0, 0, 0);
                aZ0 = __builtin_amdgcn_mfma_f32_16x16x32_f16(a0, wz[4 + kc], aZ0, 0, 0, 0);
                aR1 = __builtin_amdgcn_mfma_f32_16x16x32_f16(a1, wr[4 + kc], aR1, 0, 0, 0);
                aZ1 = __builtin_amdgcn_mfma_f32_16x16x32_f16(a1, wz[4 + kc], aZ1, 0, 0, 0);
            }
#pragma unroll
            for (int e = 0; e < 4; ++e) {
                rz_s[rb + e][cH]      = pk2(sigm(aR0[e]), sigm(aZ0[e]));
                rz_s[16 + rb + e][cH] = pk2(sigm(aR1[e]), sigm(aZ1[e]));
            }
            __syncthreads();   // B2: rz visible to N-waves
            __syncthreads();   // B3: N-waves' h/partial writes done
        }
    } else {
        // ---------------- N path ----------------
        const int cH = (wv - 8) * 16 + ln16;
        const int cN = cH + 256;
        const float bNi  = b_ih[cN];
        const float bNim = bNi + W_ih[cN * 129 + 128];
        const float bNh  = b_hh[cN];
        const float wcc  = Wc_w[cH];
        const float owc  = out_w[cH];
        half8 wn[8];
#pragma unroll
        for (int kc = 0; kc < 8; ++kc) {
            const float* pn;
            if (kc < 4) {
                pn = W_ih + cN * 129 + kc * 32 + kg * 8;
            } else {
                pn = W_hh + cN * 128 + (kc - 4) * 32 + kg * 8;
            }
#pragma unroll
            for (int e = 0; e < 8; ++e) wn[kc][e] = (_Float16)pn[e];
        }
        unsigned hpa0 = 0u, hpa1 = 0u, hpb0 = 0u, hpb1 = 0u;

        for (int t = 0; t < T_; ++t) {
            const int pb = t & 1, nb = pb ^ 1;
            phase0(t, pb);
            short4_t m4a = *(const short4_t*)&m_all[t][rb];
            short4_t m4b = *(const short4_t*)&m_all[t][16 + rb];
            f32x4 aNi0, aNi1, aNh0, aNh1;
#pragma unroll
            for (int e = 0; e < 4; ++e) {
                aNi0[e] = m4a[e] ? bNim : bNi;
                aNi1[e] = m4b[e] ? bNim : bNi;
                aNh0[e] = bNh;
                aNh1[e] = bNh;
            }
            __syncthreads();   // B1
#pragma unroll
            for (int kc = 0; kc < 4; ++kc) {
                half8 a0 = __builtin_bit_cast(half8, *(const short8_t*)&feat_s[0][kc][lane * 8]);
                half8 a1 = __builtin_bit_cast(half8, *(const short8_t*)&feat_s[1][kc][lane * 8]);
                aNi0 = __builtin_amdgcn_mfma_f32_16x16x32_f16(a0, wn[kc], aNi0, 0, 0, 0);
                aNi1 = __builtin_amdgcn_mfma_f32_16x16x32_f16(a1, wn[kc], aNi1, 0, 0, 0);
            }
#pragma unroll
            for (int kc = 0; kc < 4; ++kc) {
                half8 a0 = __builtin_bit_cast(half8, *(const short8_t*)&h_s[pb][0][kc][lane * 8]);
                half8 a1 = __builtin_bit_cast(half8, *(const short8_t*)&h_s[pb][1][kc][lane * 8]);
                aNh0 = __builtin_amdgcn_mfma_f32_16x16x32_f16(a0, wn[4 + kc], aNh0, 0, 0, 0);
                aNh1 = __builtin_amdgcn_mfma_f32_16x16x32_f16(a1, wn[4 + kc], aNh1, 0, 0, 0);
            }
            __syncthreads();   // B2: rz ready

            f32x4 hn0, hn1;
#pragma unroll
            for (int e = 0; e < 4; ++e) {
                const half2_t rz0 = h2(rz_s[rb + e][cH]);
                const half2_t rz1 = h2(rz_s[16 + rb + e][cH]);
                const float hp0 = (e < 2) ? (float)h2(hpa0)[e & 1] : (float)h2(hpa1)[e & 1];
                const float hp1 = (e < 2) ? (float)h2(hpb0)[e & 1] : (float)h2(hpb1)[e & 1];
                const float n0 = tanh_f(aNi0[e] + (float)rz0[0] * aNh0[e]);
                hn0[e] = (float)rz0[1] * (hp0 - n0) + n0;
                const float n1 = tanh_f(aNi1[e] + (float)rz1[0] * aNh1[e]);
                hn1[e] = (float)rz1[1] * (hp1 - n1) + n1;
            }
            hpa0 = pk2(hn0[0], hn0[1]); hpa1 = pk2(hn0[2], hn0[3]);
            hpb0 = pk2(hn1[0], hn1[1]); hpb1 = pk2(hn1[2], hn1[3]);

            {   // h frag writes (exactly the packed f16 values)
                const int fo = ((cH & 31) >> 3) * 128 + (cH & 7);
                short* d0 = &h_s[nb][0][cH >> 5][fo];
                short* d1 = &h_s[nb][1][cH >> 5][fo];
                d0[(rb + 0) * 8] = (short)(hpa0 & 0xffffu);
                d0[(rb + 1) * 8] = (short)(hpa0 >> 16);
                d0[(rb + 2) * 8] = (short)(hpa1 & 0xffffu);
                d0[(rb + 3) * 8] = (short)(hpa1 >> 16);
                d1[(rb + 0) * 8] = (short)(hpb0 & 0xffffu);
                d1[(rb + 1) * 8] = (short)(hpb0 >> 16);
                d1[(rb + 2) * 8] = (short)(hpb1 & 0xffffu);
                d1[(rb + 3) * 8] = (short)(hpb1 >> 16);
            }
#pragma unroll
            for (int e = 0; e < 4; ++e) {
                unsigned v0 = red16_pk(pk2(hn0[e] * wcc, hn0[e] * owc));
                unsigned v1 = red16_pk(pk2(hn1[e] * wcc, hn1[e] * owc));
                if (ln16 == 15) {
                    part_cp[nb][rb + e][wv - 8]      = v0;
                    part_cp[nb][16 + rb + e][wv - 8] = v1;
                }
            }
            __syncthreads();   // B3
        }
    }

    // final pred (t=255 partials landed in buffer 0)
    {
        uint4_t u0 = *(const uint4_t*)&part_cp[0][row][0];
        uint4_t u1 = *(const uint4_t*)&part_cp[0][row][4];
        unsigned sacc = pkadd(pkadd(pkadd(u0[0], u0[1]), pkadd(u0[2], u0[3])),
                              pkadd(pkadd(u1[0], u1[1]), pkadd(u1[2], u1[3])));
        if (tid >= 32 && tid < 64)
            pred_sh[row][T_ - 1] = h16bits((float)h2(sacc)[1] + ob);
    }
    __syncthreads();

    // coalesced output: preds [0, B*T), comps [B*T, 2*B*T)
    {
        const int orow = q;
        const int oc   = row * 8;
        short8_t pv = *(const short8_t*)&pred_sh[orow][oc];
        float* gp = out + (b0 + orow) * T_ + oc;
#pragma unroll
        for (int i = 0; i < 2; ++i) {
            f32x4 o;
            o[0] = h16f(pv[i * 4 + 0]); o[1] = h16f(pv[i * 4 + 1]);
            o[2] = h16f(pv[i * 4 + 2]); o[3] = h16f(pv[i * 4 + 3]);
            *(f32x4*)(gp + 4 * i) = o;
        }
        short8_t cv = *(const short8_t*)&comp_sh[orow][oc];
        float* gc = out + (long)B_ * T_ + (b0 + orow) * T_ + oc;
#pragma unroll
        for (int i = 0; i < 2; ++i) {
            f32x4 o;
            o[0] = h16f(cv[i * 4 + 0]); o[1] = h16f(cv[i * 4 + 1]);
            o[2] = h16f(cv[i * 4 + 2]); o[3] = h16f(cv[i * 4 + 3]);
            *(f32x4*)(gc + 4 * i) = o;
        }
    }
}

extern "C" void kernel_launch(void* const* d_in, const int* in_sizes, int n_in,
                              void* d_out, int out_size, void* d_ws, size_t ws_size,
                              hipStream_t stream) {
    const float* x_seq = (const float*)d_in[0];
    const float* m_seq = (const float*)d_in[1];
    const float* Wc_w  = (const float*)d_in[2];
    const float* Wc_b  = (const float*)d_in[3];
    const float* Wx_w  = (const float*)d_in[4];
    const float* Wx_b  = (const float*)d_in[5];
    const float* W_ih  = (const float*)d_in[6];
    const float* W_hh  = (const float*)d_in[7];
    const float* b_ih  = (const float*)d_in[8];
    const float* b_hh  = (const float*)d_in[9];
    const float* out_w = (const float*)d_in[10];
    const float* out_b = (const float*)d_in[11];
    float* out = (float*)d_out;

    dim3 grid(B_ / ROWS);   // 256 workgroups of 32 rows, 1 per CU
    dim3 block(NTH);        // 1024 threads = 16 waves, 4 waves/SIMD
    brits_kernel<<<grid, block, 0, stream>>>(x_seq, m_seq, Wc_w, Wc_b, Wx_w, Wx_b,
                                             W_ih, W_hh, b_ih, b_hh, out_w, out_b, out);
}